// Round 1
// baseline (996.134 us; speedup 1.0000x reference)
//
#include <hip/hip_runtime.h>
#include <stdint.h>

// Problem constants
#define N_ROWS 8192
#define D_DIM  1024
#define M_CENT 20000
#define M_PAD  20224          // 79 * 256
#define M_TILES 79            // 256-wide center tiles
#define Y_DIM  256
#define BM 64                 // rows of X per block
#define BN 256                // centers per M-iteration (wave tile 64x64)
#define BK 64                 // K-chunk of D
#define NCHUNK 16             // D_DIM / BK
#define MSPLIT 4
#define TILES_PER_SPLIT 20    // ceil(79/4)
#define LDSP_STRIDE 264       // 256 + 8 pad: 33 16B-slots/row ≡ 1 mod 8 -> conflict-free

typedef __attribute__((ext_vector_type(4))) float  f32x4;
typedef __attribute__((ext_vector_type(8))) __bf16 bf16x8;

__device__ __forceinline__ unsigned short f2bf(float f) {
    union { float f; unsigned u; } v; v.f = f;
    unsigned u = v.u;
    u += 0x7FFFu + ((u >> 16) & 1u);   // RNE
    return (unsigned short)(u >> 16);
}

// async global->LDS, 16B per lane. LDS dest must be wave-uniform base + lane*16.
__device__ __forceinline__ void gll16(void* lds, const void* g) {
    __builtin_amdgcn_global_load_lds(
        (const __attribute__((address_space(1))) void*)g,
        (__attribute__((address_space(3))) void*)lds, 16, 0, 0);
}

// cast fp32 rows -> bf16, compute fp32 row sum-of-squares; pad rows -> zeros
__global__ void cast_rows_kernel(const float* __restrict__ src,
                                 unsigned short* __restrict__ dst,
                                 float* __restrict__ sq, int nrows_valid) {
    int row = blockIdx.x;
    int t = threadIdx.x;  // 256 threads, 4 floats each = 1024 = D_DIM
    float s = 0.f;
    if (row < nrows_valid) {
        float4 v = ((const float4*)(src + (size_t)row * D_DIM))[t];
        s = v.x * v.x + v.y * v.y + v.z * v.z + v.w * v.w;
        ushort4 o;
        o.x = f2bf(v.x); o.y = f2bf(v.y); o.z = f2bf(v.z); o.w = f2bf(v.w);
        ((ushort4*)(dst + (size_t)row * D_DIM))[t] = o;
    } else {
        ((ushort4*)(dst + (size_t)row * D_DIM))[t] = make_ushort4(0, 0, 0, 0);
    }
    __shared__ float red[4];
    for (int off = 32; off; off >>= 1) s += __shfl_down(s, off, 64);
    if ((t & 63) == 0) red[t >> 6] = s;
    __syncthreads();
    if (t == 0) sq[row] = red[0] + red[1] + red[2] + red[3];
}

// W [M][Y] fp32 -> WT [Y][M_PAD] bf16, pad rows (centers >= M_CENT) -> 0
__global__ void cast_wT_kernel(const float* __restrict__ w,
                               unsigned short* __restrict__ wT) {
    __shared__ float tile[32][33];
    int k0 = blockIdx.x * 32;   // center dim
    int y0 = blockIdx.y * 32;   // Y dim
    int tx = threadIdx.x & 31;
    int ty = threadIdx.x >> 5;  // 0..7
    #pragma unroll
    for (int i = 0; i < 4; ++i) {
        int k = k0 + ty + i * 8;
        float v = (k < M_CENT) ? w[(size_t)k * Y_DIM + y0 + tx] : 0.f;
        tile[tx][ty + i * 8] = v;     // tile[y_local][k_local]
    }
    __syncthreads();
    #pragma unroll
    for (int i = 0; i < 4; ++i) {
        int yl = ty + i * 8;
        wT[(size_t)(y0 + yl) * M_PAD + k0 + tx] = f2bf(tile[yl][tx]);
    }
}

// ---------------------------------------------------------------------------
// Fused flash-style kernel, wave tile 64x64 (4 waves -> 64x256 S per block).
// R3 restructure (theory: barrier-drain stall, MfmaUtil 29%):
//  - Z is NOT staged in LDS anymore: each wave only reads its own 64 Z rows
//    (zero cross-wave reuse), so B-fragments come straight from global
//    (L2/L3-resident; 16B aligned loads), like Phase-3's WT already did.
//  - X (4-wave reuse) stays in LDS, double-buffered (2 x 8KB), staged with
//    gll16 + XOR swizzle (verified conflict-free pattern, unchanged).
//  - Depth-1 prefetch: chunk k issues STAGE_X(k+1) + LOAD_B(k+1) BEFORE the
//    32 MFMAs of chunk k.  The __syncthreads() at the top of chunk k+1 then
//    drains loads that are a full MFMA cluster (~1240 cyc) old -> latency
//    hidden, ONE barrier per chunk, no inline-asm waitcnt.
//    Hazards: buffer written at chunk k is buf[par^1]; its last readers
//    finished (lgkmcnt before their MFMAs) before the syncthreads separating
//    them from this stage-issue.  Reads of buf[par] are covered by the same
//    syncthreads' vmcnt(0) drain.  All waves, all cases.
//  - lds_p is disjoint from the staging buffers, so the next tile's chunk-0
//    prefetch flies during Phase 2 + Phase 3.
//  - MSPLIT 8->4: grid 512 = exact 2-blocks/CU residency, half the atomics.
//  - XCD-aware bid mapping: all 64 blocks of one XCD share a y-split ->
//    they stream the same 0.5MB Z tile through their private L2.
//  - launch_bounds(256,2): ~250 unified regs/wave (S 64 + Oacc 64 + Bf 64 +
//    working) MUST NOT spill (R2 lesson).
// ---------------------------------------------------------------------------

#define STAGE_X(PAR, KBASE) do {                                              \
    _Pragma("unroll")                                                         \
    for (int i_ = 0; i_ < 2; ++i_) {                                          \
        int lin_ = t + i_ * 256;              /* 16B unit index */            \
        int row_ = lin_ >> 3, c_ = lin_ & 7;                                  \
        gll16(&lds_x[PAR][lin_ * 8],                                          \
              Xb + (size_t)(row0 + row_) * D_DIM + (KBASE) +                  \
                  ((c_ ^ (row_ & 7)) * 8));                                   \
    } } while (0)

#define LOAD_B(DST, M0, KBASE) do {                                           \
    _Pragma("unroll")                                                         \
    for (int kt_ = 0; kt_ < 2; ++kt_)                                         \
        _Pragma("unroll")                                                     \
        for (int jt_ = 0; jt_ < 4; ++jt_)                                     \
            DST[kt_ * 4 + jt_] = *(const bf16x8*)(Zb +                        \
                (size_t)((M0) + wave * 64 + jt_ * 16 + l16) * D_DIM +         \
                (KBASE) + kt_ * 32 + quad * 8);                               \
    } while (0)

// One K-chunk: barrier, prefetch next (X->LDS dbuf, Z->regs), ds_read A,
// 32 MFMAs on current.  PAR is a literal 0/1 (static Bf indexing, rule #20).
#define CHUNK(PAR, KBASE, M0N, KBN) do {                                      \
    __syncthreads();                                                          \
    LOAD_B(Bf[PAR ^ 1], M0N, KBN);                                            \
    STAGE_X(PAR ^ 1, KBN);                                                    \
    _Pragma("unroll")                                                         \
    for (int kt_ = 0; kt_ < 2; ++kt_) {                                       \
        bf16x8 a_[4];                                                         \
        _Pragma("unroll")                                                     \
        for (int it_ = 0; it_ < 4; ++it_)                                     \
            a_[it_] = *(const bf16x8*)&lds_x[PAR][                            \
                (it_ * 16 + l16) * BK + ((kt_ * 4 + quad) ^ cx) * 8];         \
        __builtin_amdgcn_s_setprio(1);                                        \
        _Pragma("unroll")                                                     \
        for (int it_ = 0; it_ < 4; ++it_)                                     \
            _Pragma("unroll")                                                 \
            for (int jt_ = 0; jt_ < 4; ++jt_)                                 \
                S[it_ * 4 + jt_] = __builtin_amdgcn_mfma_f32_16x16x32_bf16(   \
                    a_[it_], Bf[PAR][kt_ * 4 + jt_], S[it_ * 4 + jt_],        \
                    0, 0, 0);                                                 \
        __builtin_amdgcn_s_setprio(0);                                        \
    } } while (0)

__global__ void __launch_bounds__(256, 2)
fused_kernel(const unsigned short* __restrict__ Xb,
             const unsigned short* __restrict__ Zb,
             const unsigned short* __restrict__ WbT,
             const float* __restrict__ xsq,
             const float* __restrict__ zsq,
             const int* __restrict__ bwp,
             float* __restrict__ out) {
    __shared__ unsigned short lds_x[2][BM * BK];        // 16 KB X double-buffer
    __shared__ unsigned short lds_p[BM * LDSP_STRIDE];  // 33.8 KB P tile
    __shared__ float lds_xsq[BM];                       // total ~50.4 KB -> 2 blocks/CU

    const int t    = threadIdx.x;
    const int wave = t >> 6;
    const int lane = t & 63;
    const int quad = lane >> 4;
    const int l16  = lane & 15;
    const int cx   = l16 & 7;     // row&7 of every frag row this lane touches

    // XCD-aware mapping: xcd = bid%8 gets a fixed y-split (bid&3) and 64
    // distinct x-blocks -> per-XCD L2 sees one shared Z stream.
    const int bid    = blockIdx.x;
    const int ysplit = bid & 3;
    const int xblk   = (bid >> 3) + 64 * ((bid >> 2) & 1);
    const int row0   = xblk * BM;

    int mt     = ysplit * TILES_PER_SPLIT;
    int mt_end = mt + TILES_PER_SPLIT;
    if (mt_end > M_TILES) mt_end = M_TILES;

    // bandwidth: int32 per harness convention (Python int 10); tolerate float bits too
    int bwi = *bwp;
    float bw;
    if (bwi > 0 && bwi < 1000000) bw = (float)bwi;
    else { union { int i; float f; } u; u.i = bwi; bw = u.f; }
    const float inv_bw = 1.0f / bw;

    if (t < BM) lds_xsq[t] = xsq[row0 + t];

    const f32x4 vzero = {0.f, 0.f, 0.f, 0.f};
    f32x4 Oacc[16];
    #pragma unroll
    for (int i = 0; i < 16; ++i) Oacc[i] = vzero;

    bf16x8 Bf[2][8];   // Z fragments, double-buffered in regs (64 VGPRs)

    // prologue: fill pipeline for (mt, chunk 0)
    STAGE_X(0, 0);
    LOAD_B(Bf[0], mt * BN, 0);

    for (; mt < mt_end; ++mt) {
        const int m0 = mt * BN;
        // clamp: last tile of split prefetches itself (valid mem, unused)
        const int m0next = (mt + 1 < mt_end) ? m0 + BN : m0;

        float zq[4];
        #pragma unroll
        for (int jt = 0; jt < 4; ++jt)
            zq[jt] = zsq[m0 + wave * 64 + jt * 16 + l16];

        f32x4 S[16];
        #pragma unroll
        for (int i = 0; i < 16; ++i) S[i] = vzero;

        // -------- Phase 1: S[64x256] = X * Z^T over D, depth-1 pipeline ----
        #pragma unroll 1
        for (int kc = 0; kc < NCHUNK; kc += 2) {
            const int kb0 = kc * BK;
            const int kb1 = kb0 + BK;
            const bool last = (kc + 2 == NCHUNK);
            CHUNK(0, kb0, m0, kb1);
            CHUNK(1, kb1, last ? m0next : m0, last ? 0 : kb1 + BK);
        }
        // in flight now: next tile's chunk-0 X-stage + B-frags (land during
        // Phase 2/3; lds_p is a disjoint LDS region)

        // -------- Phase 2: P = exp(-sqrt(d2)/bw) -> lds_p (bf16) --------
        #pragma unroll
        for (int it = 0; it < 4; ++it) {
            #pragma unroll
            for (int jt = 0; jt < 4; ++jt) {
                f32x4 s4 = S[it * 4 + jt];
                const int col = wave * 64 + jt * 16 + l16;
                #pragma unroll
                for (int r = 0; r < 4; ++r) {
                    const int row = it * 16 + quad * 4 + r;   // C-layout: row=(lane>>4)*4+reg
                    float d2 = lds_xsq[row] + zq[jt] - 2.0f * s4[r];
                    d2 = fmaxf(d2, 0.f);
                    float p = __expf(-sqrtf(d2) * inv_bw);
                    lds_p[row * LDSP_STRIDE + col] = f2bf(p);
                }
            }
        }
        __syncthreads();

        // -------- Phase 3: O += P[64x256] * Wtile[256x256] --------
        #pragma unroll
        for (int ks = 0; ks < 8; ++ks) {
            const int koff = ks * 32 + quad * 8;
            bf16x8 a[4], b[4];
            #pragma unroll
            for (int rt = 0; rt < 4; ++rt)
                a[rt] = *(const bf16x8*)&lds_p[(rt * 16 + l16) * LDSP_STRIDE + koff];
            #pragma unroll
            for (int ct = 0; ct < 4; ++ct) {
                const int y = wave * 64 + ct * 16 + l16;
                b[ct] = *(const bf16x8*)(WbT + (size_t)y * M_PAD + m0 + koff);
            }
            __builtin_amdgcn_s_setprio(1);
            #pragma unroll
            for (int rt = 0; rt < 4; ++rt)
                #pragma unroll
                for (int ct = 0; ct < 4; ++ct)
                    Oacc[rt * 4 + ct] = __builtin_amdgcn_mfma_f32_16x16x32_bf16(
                        a[rt], b[ct], Oacc[rt * 4 + ct], 0, 0, 0);
            __builtin_amdgcn_s_setprio(0);
        }
        // next tile's first __syncthreads separates these lds_p reads from
        // the next Phase-2 writes
    }

    // -------- epilogue: accumulate M-splits via device-scope fp32 atomics --------
    #pragma unroll
    for (int rt = 0; rt < 4; ++rt) {
        #pragma unroll
        for (int ct = 0; ct < 4; ++ct) {
            f32x4 v = Oacc[rt * 4 + ct];
            const int y = wave * 64 + ct * 16 + l16;
            #pragma unroll
            for (int r = 0; r < 4; ++r) {
                const int row = row0 + rt * 16 + quad * 4 + r;
                atomicAdd(&out[(size_t)row * Y_DIM + y], v[r]);
            }
        }
    }
}

extern "C" void kernel_launch(void* const* d_in, const int* in_sizes, int n_in,
                              void* d_out, int out_size, void* d_ws, size_t ws_size,
                              hipStream_t stream) {
    const float* X = (const float*)d_in[0];
    const float* Z = (const float*)d_in[1];
    const float* W = (const float*)d_in[2];
    const int*  bw = (const int*)d_in[3];
    float* out = (float*)d_out;

    char* ws = (char*)d_ws;
    size_t off = 0;
    unsigned short* Xb  = (unsigned short*)(ws + off); off += (size_t)N_ROWS * D_DIM * 2;
    unsigned short* Zb  = (unsigned short*)(ws + off); off += (size_t)M_PAD * D_DIM * 2;
    unsigned short* WbT = (unsigned short*)(ws + off); off += (size_t)Y_DIM * M_PAD * 2;
    float* xsq = (float*)(ws + off); off += (size_t)N_ROWS * 4;
    float* zsq = (float*)(ws + off); off += (size_t)M_PAD * 4;
    // total ws use: ~68.7 MB

    hipMemsetAsync(d_out, 0, (size_t)out_size * sizeof(float), stream);
    cast_rows_kernel<<<N_ROWS, 256, 0, stream>>>(X, Xb, xsq, N_ROWS);
    cast_rows_kernel<<<M_PAD, 256, 0, stream>>>(Z, Zb, zsq, M_CENT);
    cast_wT_kernel<<<dim3(M_PAD / 32, Y_DIM / 32), 256, 0, stream>>>(W, WbT);
    fused_kernel<<<dim3(MSPLIT * (N_ROWS / BM)), 256, 0, stream>>>(
        Xb, Zb, WbT, xsq, zsq, bw, out);
}